// Round 2
// baseline (204.657 us; speedup 1.0000x reference)
//
#include <hip/hip_runtime.h>

// B=8 images, G=32 gt/img, A=200000 anchors (B, A derived at launch).
#define G 32
#define CHUNK 1024          // anchors per K1 chunk (flag granularity for K3)
#define K1_ITER (CHUNK / 256)

// IoU must be bit-identical everywhere it's computed (exact == vs highest)
// and match numpy's unfused f32 arithmetic -> contraction off.
__device__ __forceinline__ float iou_pre(float area_g, float area_a,
                                         float g0, float g1, float g2, float g3,
                                         float a0, float a1, float a2, float a3) {
#pragma clang fp contract(off)
    float ltx = fmaxf(g0, a0), lty = fmaxf(g1, a1);
    float rbx = fminf(g2, a2), rby = fminf(g3, a3);
    float wx = fmaxf(rbx - ltx, 0.0f), wy = fmaxf(rby - lty, 0.0f);
    float inter = wx * wy;
    float uni = area_g + area_a - inter;
    return inter > 0.0f ? inter / uni : 0.0f;
}

// ---------------- fast path: single IoU pass ----------------

// K1: per (b, anchor): best iou over g + argmax (strict '>' keeps first max,
// matching jnp.argmax), stored to ws. Also per-(chunk,b,g) local max stored
// (no atomics; K2 reduces). Grid (C, B), 256 thr, 4 anchors/thread.
__global__ __launch_bounds__(256) void k1_scan(const float* __restrict__ gt,
                                               const float* __restrict__ anchors,
                                               float* __restrict__ best_out,
                                               int* __restrict__ idx_out,
                                               float* __restrict__ blockmax,
                                               int A, int B) {
#pragma clang fp contract(off)
    __shared__ float4 s_gt[G];
    __shared__ float s_area[G];
    __shared__ float s_red[4 * G];
    const int c = blockIdx.x, b = blockIdx.y, t = threadIdx.x;
    if (t < G) {
        float4 gb = ((const float4*)gt)[b * G + t];
        s_gt[t] = gb;
        s_area[t] = (gb.z - gb.x) * (gb.w - gb.y);
    }
    __syncthreads();

    float lm[G];
#pragma unroll
    for (int g = 0; g < G; ++g) lm[g] = 0.0f;  // iou >= 0

    const size_t bA = (size_t)b * (size_t)A;
    for (int k = 0; k < K1_ITER; ++k) {
        const int a = c * CHUNK + k * 256 + t;
        if (a >= A) break;
        float4 an = ((const float4*)anchors)[a];
        float aa = (an.z - an.x) * (an.w - an.y);
        float best = -1.0f;
        int idx = 0;
#pragma unroll
        for (int g = 0; g < G; ++g) {
            float4 gb = s_gt[g];
            float v = iou_pre(s_area[g], aa, gb.x, gb.y, gb.z, gb.w,
                              an.x, an.y, an.z, an.w);
            if (v > best) { best = v; idx = g; }
            lm[g] = fmaxf(lm[g], v);
        }
        best_out[bA + a] = best;
        idx_out[bA + a] = idx;
    }

    const int lane = t & 63, wid = t >> 6;
#pragma unroll
    for (int g = 0; g < G; ++g) {
        float v = lm[g];
#pragma unroll
        for (int off = 32; off > 0; off >>= 1) v = fmaxf(v, __shfl_down(v, off, 64));
        if (lane == 0) s_red[wid * G + g] = v;
    }
    __syncthreads();
    if (t < G) {
        float v = fmaxf(fmaxf(s_red[t], s_red[G + t]),
                        fmaxf(s_red[2 * G + t], s_red[3 * G + t]));
        blockmax[(c * B + b) * G + t] = v;
    }
}

// K2: hi[b*G+g] = max over chunks of blockmax. One block of B*G threads.
__global__ void k2_reduce(const float* __restrict__ blockmax,
                          float* __restrict__ hi, int C, int BG) {
    const int t = threadIdx.x;
    if (t >= BG) return;
    float v = 0.0f;
    for (int c = 0; c < C; ++c) v = fmaxf(v, blockmax[c * BG + t]);
    hi[t] = v;
}

// K3: one thread per (b,a). No IoU recompute except for gts whose hi is
// achieved inside this anchor's chunk (iou<=chunkmax<=hi makes the filter
// exact); that branch is block-uniform and almost always empty.
__global__ __launch_bounds__(256) void k3_label(const float* __restrict__ gt,
                                                const float* __restrict__ anchors,
                                                const float* __restrict__ best_in,
                                                const int* __restrict__ idx_in,
                                                const float* __restrict__ blockmax,
                                                const float* __restrict__ hi,
                                                float* __restrict__ out,
                                                int A, int B) {
#pragma clang fp contract(off)
    __shared__ float4 s_gt[G];
    __shared__ float s_hi[G];
    __shared__ unsigned s_mask;
    const int b = blockIdx.y, t = threadIdx.x;
    const int c = blockIdx.x >> 2;  // CHUNK/256 = 4 K3-blocks per chunk

    bool fl = false;
    if (t < G) {
        s_gt[t] = ((const float4*)gt)[b * G + t];
        float h = hi[b * G + t];
        s_hi[t] = h;
        fl = (blockmax[(c * B + b) * G + t] == h);
    }
    unsigned long long m = __ballot(fl);
    if (t == 0) s_mask = (unsigned)(m & 0xffffffffull);
    __syncthreads();

    const int a = blockIdx.x * 256 + t;
    if (a >= A) return;

    const float4 an = ((const float4*)anchors)[a];
    const size_t o = (size_t)b * (size_t)A + (size_t)a;
    float best = best_in[o];
    int idx = idx_in[o];

    bool lq = false;
    unsigned mask = s_mask;
    if (mask) {
        float aa = (an.z - an.x) * (an.w - an.y);
        while (mask) {
            int g = __ffs(mask) - 1;
            mask &= mask - 1;
            float4 gb = s_gt[g];
            float area_g = (gb.z - gb.x) * (gb.w - gb.y);
            float v = iou_pre(area_g, aa, gb.x, gb.y, gb.z, gb.w,
                              an.x, an.y, an.z, an.w);
            lq |= (v == s_hi[g]);
        }
    }

    int gl = (best >= 0.7f) ? 1 : ((best >= 0.3f) ? -1 : 0);
    int ol = (best >= 0.3f) ? 1 : ((best >= 0.1f) ? -1 : 0);
    if (lq) { gl = 1; ol = 1; }

    const float4 tb = s_gt[idx];
    const float cx = 0.5f * (an.x + an.z);
    const float cy = 0.5f * (an.y + an.w);
    const float w = an.z - an.x;
    const float h = an.w - an.y;
    float d0 = (cx - tb.x) / w;
    float d1 = (tb.z - cx) / w;
    float d2 = (cy - tb.y) / h;
    float d3 = (tb.w - cy) / h;
    const bool inb = (d0 >= 0.0f) && (d1 >= 0.0f) && (d2 >= 0.0f) && (d3 >= 0.0f);
    if (!inb) { d0 = d1 = d2 = d3 = 0.0f; }
    float prod = (fminf(d0, d1) / (fmaxf(d0, d1) + 1e-12f)) *
                 (fminf(d2, d3) / (fmaxf(d2, d3) + 1e-12f));
    float cen = (prod > 0.0f) ? sqrtf(prod) : 0.0f;
    if (ol == 0) cen = 0.0f;

    const size_t BA = (size_t)B * (size_t)A;
    out[o] = (float)gl;
    ((float4*)(out + BA))[o] = tb;
    out[5 * BA + o] = (float)ol;
    out[6 * BA + o] = cen;
}

// ---------------- fallback path (R1, proven) ----------------

__device__ __forceinline__ float iou_fn(float g0, float g1, float g2, float g3,
                                        float a0, float a1, float a2, float a3) {
#pragma clang fp contract(off)
    float area_g = (g2 - g0) * (g3 - g1);
    float area_a = (a2 - a0) * (a3 - a1);
    return iou_pre(area_g, area_a, g0, g1, g2, g3, a0, a1, a2, a3);
}

__global__ __launch_bounds__(256) void k_highest(const float* __restrict__ gt,
                                                 const float* __restrict__ anchors,
                                                 float* __restrict__ highest,
                                                 int A) {
#pragma clang fp contract(off)
    __shared__ float4 s_gt[G];
    __shared__ float s_red[4 * G];
    const int b = blockIdx.y;
    const int tid = threadIdx.x;
    if (tid < G) s_gt[tid] = ((const float4*)gt)[b * G + tid];
    __syncthreads();
    float lm[G];
#pragma unroll
    for (int g = 0; g < G; ++g) lm[g] = 0.0f;
    const int stride = gridDim.x * 256;
    for (int a = blockIdx.x * 256 + tid; a < A; a += stride) {
        float4 an = ((const float4*)anchors)[a];
#pragma unroll
        for (int g = 0; g < G; ++g) {
            float4 gb = s_gt[g];
            float v = iou_fn(gb.x, gb.y, gb.z, gb.w, an.x, an.y, an.z, an.w);
            lm[g] = fmaxf(lm[g], v);
        }
    }
    const int lane = tid & 63, wid = tid >> 6;
#pragma unroll
    for (int g = 0; g < G; ++g) {
        float v = lm[g];
#pragma unroll
        for (int off = 32; off > 0; off >>= 1) v = fmaxf(v, __shfl_down(v, off, 64));
        if (lane == 0) s_red[wid * G + g] = v;
    }
    __syncthreads();
    if (tid < G) {
        float v = fmaxf(fmaxf(s_red[tid], s_red[G + tid]),
                        fmaxf(s_red[2 * G + tid], s_red[3 * G + tid]));
        atomicMax((unsigned int*)&highest[b * G + tid], __float_as_uint(v));
    }
}

__global__ __launch_bounds__(256) void k_label(const float* __restrict__ gt,
                                               const float* __restrict__ anchors,
                                               const float* __restrict__ highest,
                                               float* __restrict__ out,
                                               int A, int B) {
#pragma clang fp contract(off)
    __shared__ float4 s_gt[256];
    __shared__ float s_hi[256];
    const int tid = threadIdx.x;
    const int NBG = B * G;
    if (tid < NBG) {
        s_gt[tid] = ((const float4*)gt)[tid];
        s_hi[tid] = highest[tid];
    }
    __syncthreads();
    const int a = blockIdx.x * 256 + tid;
    if (a >= A) return;
    const float4 an = ((const float4*)anchors)[a];
    const float cx = 0.5f * (an.x + an.z);
    const float cy = 0.5f * (an.y + an.w);
    const float w = an.z - an.x;
    const float h = an.w - an.y;
    const size_t BA = (size_t)B * (size_t)A;
    for (int b = 0; b < B; ++b) {
        float best = -1.0f;
        int idx = 0;
        bool lq = false;
#pragma unroll
        for (int g = 0; g < G; ++g) {
            float4 gb = s_gt[b * G + g];
            float v = iou_fn(gb.x, gb.y, gb.z, gb.w, an.x, an.y, an.z, an.w);
            if (v > best) { best = v; idx = g; }
            lq |= (v == s_hi[b * G + g]);
        }
        int gl = (best >= 0.7f) ? 1 : ((best >= 0.3f) ? -1 : 0);
        int ol = (best >= 0.3f) ? 1 : ((best >= 0.1f) ? -1 : 0);
        if (lq) { gl = 1; ol = 1; }
        const float4 tb = s_gt[b * G + idx];
        float d0 = (cx - tb.x) / w;
        float d1 = (tb.z - cx) / w;
        float d2 = (cy - tb.y) / h;
        float d3 = (tb.w - cy) / h;
        const bool inb = (d0 >= 0.0f) && (d1 >= 0.0f) && (d2 >= 0.0f) && (d3 >= 0.0f);
        if (!inb) { d0 = d1 = d2 = d3 = 0.0f; }
        float prod = (fminf(d0, d1) / (fmaxf(d0, d1) + 1e-12f)) *
                     (fminf(d2, d3) / (fmaxf(d2, d3) + 1e-12f));
        float cen = (prod > 0.0f) ? sqrtf(prod) : 0.0f;
        if (ol == 0) cen = 0.0f;
        const size_t o = (size_t)b * (size_t)A + (size_t)a;
        out[o] = (float)gl;
        ((float4*)(out + BA))[o] = tb;
        out[5 * BA + o] = (float)ol;
        out[6 * BA + o] = cen;
    }
}

extern "C" void kernel_launch(void* const* d_in, const int* in_sizes, int n_in,
                              void* d_out, int out_size, void* d_ws, size_t ws_size,
                              hipStream_t stream) {
    const float* gt = (const float*)d_in[0];       // [B, 32, 4] f32
    const float* anchors = (const float*)d_in[1];  // [A, 4] f32
    float* out = (float*)d_out;

    const int B = in_sizes[0] / (G * 4);
    const int A = in_sizes[1] / 4;
    const int C = (A + CHUNK - 1) / CHUNK;
    const int nblk = (A + 255) / 256;

    const size_t bm_bytes = (size_t)C * B * G * sizeof(float);
    const size_t ba = (size_t)B * (size_t)A;
    const size_t need = 1024 + bm_bytes + 2 * ba * 4;

    if (ws_size >= need && B * G <= 1024) {
        float* hi = (float*)d_ws;                            // B*G floats
        float* blockmax = (float*)((char*)d_ws + 1024);      // C*B*G floats
        float* best = (float*)((char*)d_ws + 1024 + bm_bytes);
        int* idx = (int*)(best + ba);
        k1_scan<<<dim3(C, B), 256, 0, stream>>>(gt, anchors, best, idx, blockmax, A, B);
        k2_reduce<<<1, B * G, 0, stream>>>(blockmax, hi, C, B * G);
        k3_label<<<dim3(nblk, B), 256, 0, stream>>>(gt, anchors, best, idx,
                                                    blockmax, hi, out, A, B);
    } else {
        float* highest = (float*)d_ws;
        hipMemsetAsync(highest, 0, (size_t)B * G * sizeof(float), stream);
        dim3 g1(64, B);
        k_highest<<<g1, 256, 0, stream>>>(gt, anchors, highest, A);
        k_label<<<nblk, 256, 0, stream>>>(gt, anchors, highest, out, A, B);
    }
}

// Round 3
// 149.640 us; speedup vs baseline: 1.3677x; 1.3677x over previous
//
#include <hip/hip_runtime.h>

// B=8 images, G=32 gt/img, A=200000 anchors (B, A derived at launch).
#define G 32
#define APT 4               // anchors per thread in k1/k3
#define CHUNK (256 * APT)   // anchors per block = flag granularity

// IoU must be bit-identical everywhere (exact == vs hi) and match numpy's
// unfused f32 arithmetic -> contraction off.
__device__ __forceinline__ float iou_pre(float area_g, float area_a,
                                         float g0, float g1, float g2, float g3,
                                         float a0, float a1, float a2, float a3) {
#pragma clang fp contract(off)
    float ltx = fmaxf(g0, a0), lty = fmaxf(g1, a1);
    float rbx = fminf(g2, a2), rby = fminf(g3, a3);
    float wx = fmaxf(rbx - ltx, 0.0f), wy = fmaxf(rby - lty, 0.0f);
    float inter = wx * wy;
    float uni = area_g + area_a - inter;
    return inter > 0.0f ? inter / uni : 0.0f;
}

__device__ __forceinline__ float centerness_fn(float4 an, float4 tb) {
#pragma clang fp contract(off)
    float cx = 0.5f * (an.x + an.z), cy = 0.5f * (an.y + an.w);
    float w = an.z - an.x, h = an.w - an.y;
    float d0 = (cx - tb.x) / w;
    float d1 = (tb.z - cx) / w;
    float d2 = (cy - tb.y) / h;
    float d3 = (tb.w - cy) / h;
    bool inb = (d0 >= 0.0f) && (d1 >= 0.0f) && (d2 >= 0.0f) && (d3 >= 0.0f);
    if (!inb) { d0 = d1 = d2 = d3 = 0.0f; }
    float prod = (fminf(d0, d1) / (fmaxf(d0, d1) + 1e-12f)) *
                 (fminf(d2, d3) / (fmaxf(d2, d3) + 1e-12f));
    return prod > 0.0f ? sqrtf(prod) : 0.0f;
}

// K1: gt-outer / anchors-in-registers inner. GT loads are wave-uniform ->
// s_load into SGPRs; no LDS in the hot loop. Writes final outputs (labels
// WITHOUT the low-quality correction; k3 patches those) + per-chunk per-gt
// max (blockmax) for the exact chunk filter.
__global__ __launch_bounds__(256) void k1_main(const float* __restrict__ gt,
                                               const float* __restrict__ anchors,
                                               float* __restrict__ out,
                                               float* __restrict__ blockmax,
                                               int A, int B) {
#pragma clang fp contract(off)
    __shared__ float4 s_gt[G];        // for epilogue indexed fetch only
    __shared__ float s_red[G * 4];
    const int c = blockIdx.x, b = blockIdx.y, t = threadIdx.x;
    if (t < G) s_gt[t] = ((const float4*)gt)[b * G + t];

    const float4* __restrict__ gt4 = (const float4*)gt;

    float4 an[APT];
    float aa[APT], best[APT];
    int bidx[APT];
    bool valid[APT];
    const int abase = c * CHUNK + t;
#pragma unroll
    for (int k = 0; k < APT; ++k) {
        int a = abase + k * 256;
        valid[k] = (a < A);
        int ac = valid[k] ? a : (A - 1);   // clamp: duplicate contributions are max-harmless
        an[k] = ((const float4*)anchors)[ac];
        aa[k] = (an[k].z - an[k].x) * (an[k].w - an[k].y);
        best[k] = -1.0f;
        bidx[k] = 0;
    }

    const int lane = t & 63, wid = t >> 6;

#pragma unroll 4
    for (int g = 0; g < G; ++g) {
        const float4 gb = gt4[b * G + g];   // uniform address -> s_load
        const float ag = (gb.z - gb.x) * (gb.w - gb.y);
        float lm = 0.0f;
#pragma unroll
        for (int k = 0; k < APT; ++k) {
            float v = iou_pre(ag, aa[k], gb.x, gb.y, gb.z, gb.w,
                              an[k].x, an[k].y, an[k].z, an[k].w);
            if (v > best[k]) { best[k] = v; bidx[k] = g; }  // strict '>': first-max, jnp.argmax
            lm = fmaxf(lm, v);
        }
#pragma unroll
        for (int off = 32; off > 0; off >>= 1) lm = fmaxf(lm, __shfl_down(lm, off, 64));
        if (lane == 0) s_red[g * 4 + wid] = lm;
    }
    __syncthreads();
    if (t < G) {
        float v = fmaxf(fmaxf(s_red[t * 4 + 0], s_red[t * 4 + 1]),
                        fmaxf(s_red[t * 4 + 2], s_red[t * 4 + 3]));
        blockmax[(c * B + b) * G + t] = v;
    }

    const size_t BA = (size_t)B * (size_t)A;
    const size_t bA = (size_t)b * (size_t)A;
#pragma unroll
    for (int k = 0; k < APT; ++k) {
        if (!valid[k]) continue;
        const size_t o = bA + (size_t)(abase + k * 256);
        int gl = (best[k] >= 0.7f) ? 1 : ((best[k] >= 0.3f) ? -1 : 0);
        int ol = (best[k] >= 0.3f) ? 1 : ((best[k] >= 0.1f) ? -1 : 0);
        const float4 tb = s_gt[bidx[k]];
        float cen = centerness_fn(an[k], tb);
        if (ol == 0) cen = 0.0f;
        out[o] = (float)gl;
        ((float4*)(out + BA))[o] = tb;
        out[5 * BA + o] = (float)ol;
        out[6 * BA + o] = cen;
    }
}

// K2: hi[bg] = max over C chunks of blockmax. One block (64 thr) per (b,g).
__global__ void k2_reduce(const float* __restrict__ blockmax,
                          float* __restrict__ hi, int C, int BG) {
    const int bg = blockIdx.x, t = threadIdx.x;
    float v = 0.0f;
    for (int c = t; c < C; c += 64) v = fmaxf(v, blockmax[c * BG + bg]);
#pragma unroll
    for (int off = 32; off > 0; off >>= 1) v = fmaxf(v, __shfl_down(v, off, 64));
    if (t == 0) hi[bg] = v;
}

// K3: low-quality patch. A chunk can contain an anchor with iou==hi[g] only
// if its blockmax[g]==hi[g] (iou<=chunkmax<=hi, values bit-exact). ~99.7% of
// blocks exit on mask==0. Flagged blocks rescan with code bit-identical to
// k1 (same g order, same ops) and rewrite gl/ol/cen where v==hi[g]; the
// matched box is unchanged (same argmax).
__global__ __launch_bounds__(256) void k3_patch(const float* __restrict__ gt,
                                                const float* __restrict__ anchors,
                                                const float* __restrict__ blockmax,
                                                const float* __restrict__ hi,
                                                float* __restrict__ out,
                                                int A, int B) {
#pragma clang fp contract(off)
    __shared__ float4 s_gt[G];
    __shared__ float s_hi[G];
    __shared__ unsigned s_mask;
    const int c = blockIdx.x, b = blockIdx.y, t = threadIdx.x;
    bool fl = false;
    if (t < G) {
        float h = hi[b * G + t];
        s_hi[t] = h;
        s_gt[t] = ((const float4*)gt)[b * G + t];
        fl = (blockmax[(c * B + b) * G + t] == h);
    }
    unsigned long long m = __ballot(fl);
    if (t == 0) s_mask = (unsigned)(m & 0xffffffffull);
    __syncthreads();
    if (s_mask == 0) return;

    const float4* __restrict__ gt4 = (const float4*)gt;
    const size_t BA = (size_t)B * (size_t)A;
    const size_t bA = (size_t)b * (size_t)A;
    const int abase = c * CHUNK + t;

    float4 an[APT];
    float aa[APT], best[APT];
    int bidx[APT];
    bool valid[APT], lq[APT];
#pragma unroll
    for (int k = 0; k < APT; ++k) {
        int a = abase + k * 256;
        valid[k] = (a < A);
        int ac = valid[k] ? a : (A - 1);
        an[k] = ((const float4*)anchors)[ac];
        aa[k] = (an[k].z - an[k].x) * (an[k].w - an[k].y);
        best[k] = -1.0f;
        bidx[k] = 0;
        lq[k] = false;
    }

#pragma unroll 4
    for (int g = 0; g < G; ++g) {
        const float4 gb = gt4[b * G + g];
        const float ag = (gb.z - gb.x) * (gb.w - gb.y);
        const float hg = s_hi[g];
#pragma unroll
        for (int k = 0; k < APT; ++k) {
            float v = iou_pre(ag, aa[k], gb.x, gb.y, gb.z, gb.w,
                              an[k].x, an[k].y, an[k].z, an[k].w);
            if (v > best[k]) { best[k] = v; bidx[k] = g; }
            lq[k] |= (v == hg);   // non-flagged g can never hit (v<=blockmax<hi)
        }
    }

#pragma unroll
    for (int k = 0; k < APT; ++k) {
        if (!valid[k] || !lq[k]) continue;
        const size_t o = bA + (size_t)(abase + k * 256);
        const float4 tb = s_gt[bidx[k]];
        float cen = centerness_fn(an[k], tb);   // ol becomes 1 -> unmasked
        out[o] = 1.0f;
        out[5 * BA + o] = 1.0f;
        out[6 * BA + o] = cen;
    }
}

extern "C" void kernel_launch(void* const* d_in, const int* in_sizes, int n_in,
                              void* d_out, int out_size, void* d_ws, size_t ws_size,
                              hipStream_t stream) {
    const float* gt = (const float*)d_in[0];       // [B, 32, 4] f32
    const float* anchors = (const float*)d_in[1];  // [A, 4] f32
    float* out = (float*)d_out;

    const int B = in_sizes[0] / (G * 4);
    const int A = in_sizes[1] / 4;
    const int C = (A + CHUNK - 1) / CHUNK;
    const int BG = B * G;

    float* hi = (float*)d_ws;                        // BG floats
    float* blockmax = (float*)((char*)d_ws + 1024);  // C*BG floats (~200 KB; ws >= 13 MB per R2)

    k1_main<<<dim3(C, B), 256, 0, stream>>>(gt, anchors, out, blockmax, A, B);
    k2_reduce<<<BG, 64, 0, stream>>>(blockmax, hi, C, BG);
    k3_patch<<<dim3(C, B), 256, 0, stream>>>(gt, anchors, blockmax, hi, out, A, B);
}